// Round 9
// baseline (193.741 us; speedup 1.0000x reference)
//
#include <hip/hip_runtime.h>

#define N_ROWS 32768
#define D_IN 320
#define CB 16
#define N_BOOKS 8192

typedef __attribute__((ext_vector_type(8))) short bf16x8;
typedef __attribute__((ext_vector_type(4))) float f32x4;
#define MFMA __builtin_amdgcn_mfma_f32_16x16x32_bf16
#define AS1 __attribute__((address_space(1)))
#define AS3 __attribute__((address_space(3)))

__device__ __forceinline__ unsigned short bf16rn(float f) {
  unsigned u = __float_as_uint(f);
  u += 0x7fffu + ((u >> 16) & 1u);
  return (unsigned short)(u >> 16);
}
__device__ __forceinline__ float bf16tof(unsigned short h) {
  return __uint_as_float(((unsigned)h) << 16);
}
// async global->LDS, 16B per lane; lds ptr must be wave-uniform base
__device__ __forceinline__ void gload_lds16(const short* g, short* l) {
  __builtin_amdgcn_global_load_lds((const AS1 unsigned int*)g, (AS3 unsigned int*)l, 16, 0, 0);
}

// ---------------- Kernel 1 (fused): proj (blocks 0..511) + codebook prep (512..543) -------
// prep: 2-SPLIT bfrag[bt][split][lane][8]; B1=[c1|c1], B2=[c2|c2]; tile = 1024 shorts.
// nh = -0.5||c||^2 (fp64).
// proj: targets = X @ W^T via bf16 3-split MFMA, f32 chained accumulators.
__global__ __launch_bounds__(256, 2) void proj_prep_kernel(
    const float* __restrict__ x, const float* __restrict__ w, short* __restrict__ tsplit,
    const float* __restrict__ cbk, short* __restrict__ bfrag, float* __restrict__ nh_g) {
  __shared__ __align__(16) short wfrag[3][10][64][8];  // 30720 B
  __shared__ __align__(16) float xs[2][64 * 36];       // 18432 B
  const int tid = threadIdx.x;

  if (blockIdx.x >= 512) {  // ---- prep branch (no LDS, no syncthreads) ----
    const int bid = blockIdx.x - 512;
    const int j = bid * 256 + tid;
    const float4* src = (const float4*)(cbk + (size_t)j * CB);
    float4 a = src[0], b = src[1], c = src[2], d = src[3];
    float ce[16] = {a.x, a.y, a.z, a.w, b.x, b.y, b.z, b.w,
                    c.x, c.y, c.z, c.w, d.x, d.y, d.z, d.w};
    short c1[16], c2[16];
    double s = 0.0;
#pragma unroll
    for (int i = 0; i < 16; i++) {
      s += (double)ce[i] * (double)ce[i];
      unsigned short x1 = bf16rn(ce[i]);
      float r1 = ce[i] - bf16tof(x1);
      unsigned short x2 = bf16rn(r1);
      c1[i] = (short)x1; c2[i] = (short)x2;
    }
    nh_g[j] = (float)(-0.5 * s);
    bf16x8 lo1, hi1, lo2, hi2;
#pragma unroll
    for (int i = 0; i < 8; i++) {
      lo1[i] = c1[i]; hi1[i] = c1[i + 8];
      lo2[i] = c2[i]; hi2[i] = c2[i + 8];
    }
    const int bt = j >> 4, n = j & 15;
    short* base = bfrag + (size_t)bt * 1024;
    *(bf16x8*)(base + (0 * 16 + n) * 8) = lo1;
    *(bf16x8*)(base + (1 * 16 + n) * 8) = hi1;
    *(bf16x8*)(base + (2 * 16 + n) * 8) = lo1;
    *(bf16x8*)(base + (3 * 16 + n) * 8) = hi1;
    *(bf16x8*)(base + 512 + (0 * 16 + n) * 8) = lo2;
    *(bf16x8*)(base + 512 + (1 * 16 + n) * 8) = hi2;
    *(bf16x8*)(base + 512 + (2 * 16 + n) * 8) = lo2;
    *(bf16x8*)(base + 512 + (3 * 16 + n) * 8) = hi2;
    return;
  }

  // ---- proj branch ----
  const int lane = tid & 63;
  const int wv = tid >> 6;

  for (int i = tid; i < D_IN * CB; i += 256) {
    int d = i >> 4, o = i & 15;
    float f = w[o * D_IN + d];
    unsigned short h1 = bf16rn(f);
    float r1 = f - bf16tof(h1);
    unsigned short h2 = bf16rn(r1);
    float r2 = r1 - bf16tof(h2);
    unsigned short h3 = bf16rn(r2);
    int c = d >> 5, qq = (d >> 3) & 3, pos = d & 7;
    int ln = qq * 16 + o;
    wfrag[0][c][ln][pos] = (short)h1;
    wfrag[1][c][ln][pos] = (short)h2;
    wfrag[2][c][ln][pos] = (short)h3;
  }

  const float* xblk = x + (size_t)blockIdx.x * 64 * D_IN;
  {
    int row = tid >> 2, k0 = (tid & 3) * 8;
    float4 v0 = *(const float4*)(xblk + row * D_IN + k0);
    float4 v1 = *(const float4*)(xblk + row * D_IN + k0 + 4);
    *(float4*)&xs[0][row * 36 + k0] = v0;
    *(float4*)&xs[0][row * 36 + k0 + 4] = v1;
  }
  __syncthreads();

  const int m = lane & 15, q = lane >> 4;
  f32x4 g1 = {0.f, 0.f, 0.f, 0.f}, g2 = {0.f, 0.f, 0.f, 0.f}, g3 = {0.f, 0.f, 0.f, 0.f};
  for (int c = 0; c < 10; c++) {
    const int buf = c & 1;
    if (c < 9) {
      int row = tid >> 2, k0 = (tid & 3) * 8;
      float4 v0 = *(const float4*)(xblk + row * D_IN + (c + 1) * 32 + k0);
      float4 v1 = *(const float4*)(xblk + row * D_IN + (c + 1) * 32 + k0 + 4);
      *(float4*)&xs[buf ^ 1][row * 36 + k0] = v0;
      *(float4*)&xs[buf ^ 1][row * 36 + k0 + 4] = v1;
    }
    const float* xp = &xs[buf][(wv * 16 + m) * 36 + q * 8];
    float4 xa = *(const float4*)xp;
    float4 xb = *(const float4*)(xp + 4);
    float xe[8] = {xa.x, xa.y, xa.z, xa.w, xb.x, xb.y, xb.z, xb.w};
    bf16x8 a1, a2, a3;
#pragma unroll
    for (int j = 0; j < 8; j++) {
      unsigned short h1 = bf16rn(xe[j]);
      float r1 = xe[j] - bf16tof(h1);
      unsigned short h2 = bf16rn(r1);
      float r2 = r1 - bf16tof(h2);
      unsigned short h3 = bf16rn(r2);
      a1[j] = (short)h1; a2[j] = (short)h2; a3[j] = (short)h3;
    }
    bf16x8 b1 = *(const bf16x8*)wfrag[0][c][lane];
    bf16x8 b2 = *(const bf16x8*)wfrag[1][c][lane];
    bf16x8 b3 = *(const bf16x8*)wfrag[2][c][lane];
    g1 = MFMA(a1, b1, g1, 0, 0, 0);
    g2 = MFMA(a2, b1, g2, 0, 0, 0);
    g2 = MFMA(a1, b2, g2, 0, 0, 0);
    g3 = MFMA(a3, b1, g3, 0, 0, 0);
    g3 = MFMA(a1, b3, g3, 0, 0, 0);
    g3 = MFMA(a2, b2, g3, 0, 0, 0);
    __syncthreads();
  }

  float* tl = (float*)xs;  // 64 rows x stride 17
#pragma unroll
  for (int r = 0; r < 4; r++) {
    double t = (double)g1[r] + ((double)g2[r] + (double)g3[r]);
    tl[(wv * 16 + q * 4 + r) * 17 + m] = (float)t;
  }
  __syncthreads();
  {
    int row_l = tid >> 2, p = tid & 3;
    short h1[4], h2[4], h3[4];
#pragma unroll
    for (int i = 0; i < 4; i++) {
      float f = tl[row_l * 17 + p * 4 + i];
      unsigned short a = bf16rn(f);
      float r1 = f - bf16tof(a);
      unsigned short b = bf16rn(r1);
      float r2 = r1 - bf16tof(b);
      unsigned short cc = bf16rn(r2);
      h1[i] = (short)a; h2[i] = (short)b; h3[i] = (short)cc;
    }
    size_t base = (size_t)(blockIdx.x * 64 + row_l) * 48;
    *(short4*)(tsplit + base + p * 4) = make_short4(h1[0], h1[1], h1[2], h1[3]);
    *(short4*)(tsplit + base + 16 + p * 4) = make_short4(h2[0], h2[1], h2[2], h2[3]);
    *(short4*)(tsplit + base + 32 + p * 4) = make_short4(h3[0], h3[1], h3[2], h3[3]);
  }
}

// ---------------- Kernel 2: R8 structure, 8-WAVE blocks x 2 row-tiles/wave ----------------
// R9: occupancy was reg-capped, not LDS-capped (R8: 29% ~= 2 waves/SIMD despite LDS/grid
// permitting 50% -> unified VGPR+AGPR >128/thread; fmed3/fmax can't read AGPRs so top-2
// updates paid accvgpr round-trips). 512-thread blocks, 2 rt/wave: SAME 256 rows + 64KB
// staging + 8 barriers per block (not R2/R6 work-dilution), but per-wave live state halves
// (A12[2]=8 + s1/s2[2][4]=16 + bfrags 16 + acc 4 ~= 60 regs) -> target 6-8 waves/SIMD.
#define SC_H 8

__global__ __launch_bounds__(512, 2) void score_kernel(const short* __restrict__ tsplit,
                                                       const short* __restrict__ bfrag,
                                                       const float* __restrict__ nh_g,
                                                       float4* __restrict__ cand) {
  __shared__ __align__(16) short ldsb[2][8192];  // 2 x 16 KB
  __shared__ float ldsnh[1024];                  // 4 KB
  const int tid = threadIdx.x;
  const int lane = tid & 63;
  const int wv = tid >> 6;  // 0..7
  const int m = lane & 15, q = lane >> 4;
  const int rb = blockIdx.x & 127;
  const int h = blockIdx.x >> 7;  // 0..7
  const int rowbase = rb * 256;

  // A-frags from prepacked tsplit: A12 = [t1|t2]; wave covers rows wv*32 .. wv*32+31
  bf16x8 A12[2];
#pragma unroll
  for (int rt = 0; rt < 2; rt++) {
    int row = rowbase + wv * 32 + rt * 16 + m;
    A12[rt] = *(const bf16x8*)(tsplit + (size_t)row * 48 + q * 8);
  }
  for (int i = tid; i < 1024; i += 512) ldsnh[i] = nh_g[h * 1024 + i];

  const short* gq = bfrag + (size_t)h * 65536;  // this eighth: 64 tiles x 1024 shorts
  {  // stage substage 0: 8 waves x 2 rounds x 512 shorts = 8192 shorts (16 KB)
    const short* g0 = gq + wv * 1024 + lane * 8;
    gload_lds16(g0, &ldsb[0][wv * 1024]);
    gload_lds16(g0 + 512, &ldsb[0][wv * 1024 + 512]);
  }

  const unsigned qmask = 0xFFFFFFC0u;
  float s1[2][4], s2[2][4];
#pragma unroll
  for (int rt = 0; rt < 2; rt++)
#pragma unroll
    for (int r = 0; r < 4; r++) { s1[rt][r] = -3.4e38f; s2[rt][r] = -3.4e38f; }

  __syncthreads();  // drains substage-0 loads + nh writes

  for (int sc = 0; sc < 8; sc++) {
    const int cur = sc & 1;
    if (sc < 7) {  // async prefetch next substage into other buffer
      const short* gs = gq + (sc + 1) * 8192 + wv * 1024 + lane * 8;
      gload_lds16(gs, &ldsb[cur ^ 1][wv * 1024]);
      gload_lds16(gs + 512, &ldsb[cur ^ 1][wv * 1024 + 512]);
    }
#pragma unroll
    for (int bt = 0; bt < 8; bt++) {
      const short* bp = &ldsb[cur][bt * 1024];
      bf16x8 b1 = *(const bf16x8*)(bp + lane * 8);
      bf16x8 b2 = *(const bf16x8*)(bp + 512 + lane * 8);
      const int btg = sc * 8 + bt;
      float nh0 = ldsnh[btg * 16 + m];
      f32x4 ci = {nh0, nh0, nh0, nh0};
      const unsigned tagv = (unsigned)(63 - btg);  // prefer low bt on quantized ties
#pragma unroll
      for (int rt = 0; rt < 2; rt++) {
        f32x4 acc = MFMA(A12[rt], b1, ci, 0, 0, 0);
        acc = MFMA(A12[rt], b2, acc, 0, 0, 0);
#pragma unroll
        for (int r = 0; r < 4; r++) {
          float vq = __uint_as_float((__float_as_uint(acc[r]) & qmask) | tagv);
          s2[rt][r] = __builtin_amdgcn_fmed3f(vq, s1[rt][r], s2[rt][r]);
          s1[rt][r] = fmaxf(s1[rt][r], vq);
        }
      }
    }
    __syncthreads();  // readers done with cur; prefetch into cur^1 drained
  }

  // cross-lane top-2 merge over 16 column-lanes; index recovered from tag + ballot
#pragma unroll
  for (int rt = 0; rt < 2; rt++)
#pragma unroll
    for (int r = 0; r < 4; r++) {
      float s1v = s1[rt][r], s2v = s2[rt][r];
      const float ps1 = s1v;  // pre-merge value: identifies the owner lane
#pragma unroll
      for (int msk = 1; msk <= 8; msk <<= 1) {
        float o1 = __shfl_xor(s1v, msk);
        float o2 = __shfl_xor(s2v, msk);
        s2v = __builtin_amdgcn_fmed3f(s1v, o1, fmaxf(s2v, o2));
        s1v = fmaxf(s1v, o1);
      }
      unsigned long long bal = __ballot(ps1 == s1v);
      unsigned grp = (unsigned)((bal >> (q * 16)) & 0xFFFFull);
      int mwin = __builtin_ctz(grp | 0x10000u);  // grp!=0 guaranteed; | is safety
      int btwin = 63 - (int)(__float_as_uint(s1v) & 63u);
      int col = h * 1024 + btwin * 16 + mwin;
      if (m == 0) {
        int row = rowbase + wv * 32 + rt * 16 + q * 4 + r;
        cand[(size_t)h * N_ROWS + row] = make_float4(s1v, s2v, __int_as_float(col), 0.f);
      }
    }
}

// ---------------- Kernel 3 (fused): merge eighths + flag + exact fp64 rescore -------------
// eps 1e-3 covers: 2-split error (~2e-4) + mantissa quantization (<=2.4e-4). Expected
// flagged rows chip-wide ~tens (gap ~ sigma/4.2 ~ 1.3 >> eps); block-local LDS list, each
// block rescores its own flagged rows (usually 0) -> no global list/ctr, one fewer launch.
#define MARGIN_EPS 1.0e-3f

__global__ __launch_bounds__(256) void merge_rescore_kernel(const float4* __restrict__ cand,
                                                            const float* __restrict__ x,
                                                            const float* __restrict__ w,
                                                            const float* __restrict__ codebook,
                                                            int* __restrict__ out) {
  __shared__ int lcount;
  __shared__ int llist[256];
  __shared__ double ps[16][17];
  __shared__ double tsh[16];
  __shared__ double rs[256];
  __shared__ int ri[256];
  const int tid = threadIdx.x;
  const int base = blockIdx.x * 256;
  if (tid == 0) lcount = 0;
  __syncthreads();
  {  // merge 8 eighths (ascending + strict '>' => min index on ties)
    const int r = base + tid;
    float S1 = -3.4e38f, S2 = -3.4e38f;
    int I = 0;
#pragma unroll
    for (int h = 0; h < SC_H; h++) {
      float4 v = cand[(size_t)h * N_ROWS + r];
      if (v.x > S1) {
        S2 = fmaxf(S1, v.y); S1 = v.x; I = __float_as_int(v.z);
      } else {
        S2 = fmaxf(S2, v.x);
      }
    }
    out[r] = I;
    if (S1 - S2 < MARGIN_EPS) {
      int s = atomicAdd(&lcount, 1);  // LDS-scope atomic
      llist[s] = r;
    }
  }
  __syncthreads();
  const int total = lcount;  // block-uniform

  for (int it = 0; it < total; it++) {
    const int row = llist[it];
    {  // exact fp64 t = x_row . W^T
      int o = tid & 15, c = tid >> 4;
      double p = 0.0;
      for (int k = 0; k < 20; k++) {
        int d = c * 20 + k;
        p = fma((double)x[(size_t)row * D_IN + d], (double)w[o * D_IN + d], p);
      }
      ps[c][o] = p;
    }
    __syncthreads();
    if (tid < 16) {
      double t = 0.0;
      for (int c = 0; c < 16; c++) t += ps[c][tid];
      tsh[tid] = t;
    }
    __syncthreads();
    double t[16];
#pragma unroll
    for (int i = 0; i < 16; i++) t[i] = tsh[i];
    double bs = -1.0e300;
    int bi = 0;
    for (int j = tid; j < N_BOOKS; j += 256) {
      const float* cp = codebook + (size_t)j * CB;
      double dot = 0.0, cc = 0.0;
#pragma unroll
      for (int i = 0; i < 16; i++) {
        double cv = (double)cp[i];
        dot = fma(t[i], cv, dot);
        cc = fma(cv, cv, cc);
      }
      double mv = dot - 0.5 * cc;
      if (mv > bs) { bs = mv; bi = j; }  // ascending j: first wins
    }
    rs[tid] = bs; ri[tid] = bi;
    __syncthreads();
    for (int s = 128; s > 0; s >>= 1) {
      if (tid < s) {
        double os = rs[tid + s]; int oi = ri[tid + s];
        if (os > rs[tid] || (os == rs[tid] && oi < ri[tid])) { rs[tid] = os; ri[tid] = oi; }
      }
      __syncthreads();
    }
    if (tid == 0) out[row] = ri[0];
    __syncthreads();  // protect ps/rs reuse on next list item
  }
}

extern "C" void kernel_launch(void* const* d_in, const int* in_sizes, int n_in,
                              void* d_out, int out_size, void* d_ws, size_t ws_size,
                              hipStream_t stream) {
  (void)in_sizes; (void)n_in; (void)out_size; (void)ws_size;
  const float* x = (const float*)d_in[0];
  // d_in[1] = mask_time_indices: all-ones -> flatten; unused
  const float* w = (const float*)d_in[2];
  const float* codebook = (const float*)d_in[3];

  char* ws = (char*)d_ws;
  short* tsplit = (short*)(ws);              // 3 MB   (32768 x 48 shorts)
  short* bfrag = (short*)(ws + (3 << 20));   // 1 MB   (512 bt x 1024 shorts)
  float* nh_g = (float*)(ws + (4 << 20));    // 32 KB
  float4* cand = (float4*)(ws + (5 << 20));  // 4 MB   (8 x 32768 x 16 B)
  int* out = (int*)d_out;

  proj_prep_kernel<<<512 + N_BOOKS / 256, 256, 0, stream>>>(x, w, tsplit, codebook, bfrag,
                                                            nh_g);
  score_kernel<<<128 * SC_H, 512, 0, stream>>>(tsplit, bfrag, nh_g, cand);
  merge_rescore_kernel<<<N_ROWS / 256, 256, 0, stream>>>(cand, x, w, codebook, out);
}

// Round 10
// 175.740 us; speedup vs baseline: 1.1024x; 1.1024x over previous
//
#include <hip/hip_runtime.h>

#define N_ROWS 32768
#define D_IN 320
#define CB 16
#define N_BOOKS 8192

typedef __attribute__((ext_vector_type(8))) short bf16x8;
typedef __attribute__((ext_vector_type(4))) float f32x4;
#define MFMA __builtin_amdgcn_mfma_f32_16x16x32_bf16
#define AS1 __attribute__((address_space(1)))
#define AS3 __attribute__((address_space(3)))

__device__ __forceinline__ unsigned short bf16rn(float f) {
  unsigned u = __float_as_uint(f);
  u += 0x7fffu + ((u >> 16) & 1u);
  return (unsigned short)(u >> 16);
}
__device__ __forceinline__ float bf16tof(unsigned short h) {
  return __uint_as_float(((unsigned)h) << 16);
}
// async global->LDS, 16B per lane; lds ptr must be wave-uniform base
__device__ __forceinline__ void gload_lds16(const short* g, short* l) {
  __builtin_amdgcn_global_load_lds((const AS1 unsigned int*)g, (AS3 unsigned int*)l, 16, 0, 0);
}

// ---------------- Kernel 1 (fused): proj (blocks 0..511) + codebook prep (512..543) -------
// prep: 2-SPLIT bfrag[bt][split][lane][8]; B1=[c1|c1], B2=[c2|c2]; tile = 1024 shorts.
// nh = -0.5||c||^2 (fp64). Zeroes flagged-row counter.
// proj: targets = X @ W^T via bf16 3-split MFMA, f32 chained accumulators.
__global__ __launch_bounds__(256, 2) void proj_prep_kernel(
    const float* __restrict__ x, const float* __restrict__ w, short* __restrict__ tsplit,
    const float* __restrict__ cbk, short* __restrict__ bfrag, float* __restrict__ nh_g,
    int* __restrict__ ctr) {
  __shared__ __align__(16) short wfrag[3][10][64][8];  // 30720 B
  __shared__ __align__(16) float xs[2][64 * 36];       // 18432 B
  const int tid = threadIdx.x;

  if (blockIdx.x >= 512) {  // ---- prep branch (no LDS, no syncthreads) ----
    const int bid = blockIdx.x - 512;
    if (bid == 0 && tid == 0) *ctr = 0;
    const int j = bid * 256 + tid;
    const float4* src = (const float4*)(cbk + (size_t)j * CB);
    float4 a = src[0], b = src[1], c = src[2], d = src[3];
    float ce[16] = {a.x, a.y, a.z, a.w, b.x, b.y, b.z, b.w,
                    c.x, c.y, c.z, c.w, d.x, d.y, d.z, d.w};
    short c1[16], c2[16];
    double s = 0.0;
#pragma unroll
    for (int i = 0; i < 16; i++) {
      s += (double)ce[i] * (double)ce[i];
      unsigned short x1 = bf16rn(ce[i]);
      float r1 = ce[i] - bf16tof(x1);
      unsigned short x2 = bf16rn(r1);
      c1[i] = (short)x1; c2[i] = (short)x2;
    }
    nh_g[j] = (float)(-0.5 * s);
    bf16x8 lo1, hi1, lo2, hi2;
#pragma unroll
    for (int i = 0; i < 8; i++) {
      lo1[i] = c1[i]; hi1[i] = c1[i + 8];
      lo2[i] = c2[i]; hi2[i] = c2[i + 8];
    }
    const int bt = j >> 4, n = j & 15;
    short* base = bfrag + (size_t)bt * 1024;
    *(bf16x8*)(base + (0 * 16 + n) * 8) = lo1;
    *(bf16x8*)(base + (1 * 16 + n) * 8) = hi1;
    *(bf16x8*)(base + (2 * 16 + n) * 8) = lo1;
    *(bf16x8*)(base + (3 * 16 + n) * 8) = hi1;
    *(bf16x8*)(base + 512 + (0 * 16 + n) * 8) = lo2;
    *(bf16x8*)(base + 512 + (1 * 16 + n) * 8) = hi2;
    *(bf16x8*)(base + 512 + (2 * 16 + n) * 8) = lo2;
    *(bf16x8*)(base + 512 + (3 * 16 + n) * 8) = hi2;
    return;
  }

  // ---- proj branch ----
  const int lane = tid & 63;
  const int wv = tid >> 6;

  for (int i = tid; i < D_IN * CB; i += 256) {
    int d = i >> 4, o = i & 15;
    float f = w[o * D_IN + d];
    unsigned short h1 = bf16rn(f);
    float r1 = f - bf16tof(h1);
    unsigned short h2 = bf16rn(r1);
    float r2 = r1 - bf16tof(h2);
    unsigned short h3 = bf16rn(r2);
    int c = d >> 5, qq = (d >> 3) & 3, pos = d & 7;
    int ln = qq * 16 + o;
    wfrag[0][c][ln][pos] = (short)h1;
    wfrag[1][c][ln][pos] = (short)h2;
    wfrag[2][c][ln][pos] = (short)h3;
  }

  const float* xblk = x + (size_t)blockIdx.x * 64 * D_IN;
  {
    int row = tid >> 2, k0 = (tid & 3) * 8;
    float4 v0 = *(const float4*)(xblk + row * D_IN + k0);
    float4 v1 = *(const float4*)(xblk + row * D_IN + k0 + 4);
    *(float4*)&xs[0][row * 36 + k0] = v0;
    *(float4*)&xs[0][row * 36 + k0 + 4] = v1;
  }
  __syncthreads();

  const int m = lane & 15, q = lane >> 4;
  f32x4 g1 = {0.f, 0.f, 0.f, 0.f}, g2 = {0.f, 0.f, 0.f, 0.f}, g3 = {0.f, 0.f, 0.f, 0.f};
  for (int c = 0; c < 10; c++) {
    const int buf = c & 1;
    if (c < 9) {
      int row = tid >> 2, k0 = (tid & 3) * 8;
      float4 v0 = *(const float4*)(xblk + row * D_IN + (c + 1) * 32 + k0);
      float4 v1 = *(const float4*)(xblk + row * D_IN + (c + 1) * 32 + k0 + 4);
      *(float4*)&xs[buf ^ 1][row * 36 + k0] = v0;
      *(float4*)&xs[buf ^ 1][row * 36 + k0 + 4] = v1;
    }
    const float* xp = &xs[buf][(wv * 16 + m) * 36 + q * 8];
    float4 xa = *(const float4*)xp;
    float4 xb = *(const float4*)(xp + 4);
    float xe[8] = {xa.x, xa.y, xa.z, xa.w, xb.x, xb.y, xb.z, xb.w};
    bf16x8 a1, a2, a3;
#pragma unroll
    for (int j = 0; j < 8; j++) {
      unsigned short h1 = bf16rn(xe[j]);
      float r1 = xe[j] - bf16tof(h1);
      unsigned short h2 = bf16rn(r1);
      float r2 = r1 - bf16tof(h2);
      unsigned short h3 = bf16rn(r2);
      a1[j] = (short)h1; a2[j] = (short)h2; a3[j] = (short)h3;
    }
    bf16x8 b1 = *(const bf16x8*)wfrag[0][c][lane];
    bf16x8 b2 = *(const bf16x8*)wfrag[1][c][lane];
    bf16x8 b3 = *(const bf16x8*)wfrag[2][c][lane];
    g1 = MFMA(a1, b1, g1, 0, 0, 0);
    g2 = MFMA(a2, b1, g2, 0, 0, 0);
    g2 = MFMA(a1, b2, g2, 0, 0, 0);
    g3 = MFMA(a3, b1, g3, 0, 0, 0);
    g3 = MFMA(a1, b3, g3, 0, 0, 0);
    g3 = MFMA(a2, b2, g3, 0, 0, 0);
    __syncthreads();
  }

  float* tl = (float*)xs;  // 64 rows x stride 17
#pragma unroll
  for (int r = 0; r < 4; r++) {
    double t = (double)g1[r] + ((double)g2[r] + (double)g3[r]);
    tl[(wv * 16 + q * 4 + r) * 17 + m] = (float)t;
  }
  __syncthreads();
  {
    int row_l = tid >> 2, p = tid & 3;
    short h1[4], h2[4], h3[4];
#pragma unroll
    for (int i = 0; i < 4; i++) {
      float f = tl[row_l * 17 + p * 4 + i];
      unsigned short a = bf16rn(f);
      float r1 = f - bf16tof(a);
      unsigned short b = bf16rn(r1);
      float r2 = r1 - bf16tof(b);
      unsigned short cc = bf16rn(r2);
      h1[i] = (short)a; h2[i] = (short)b; h3[i] = (short)cc;
    }
    size_t base = (size_t)(blockIdx.x * 64 + row_l) * 48;
    *(short4*)(tsplit + base + p * 4) = make_short4(h1[0], h1[1], h1[2], h1[3]);
    *(short4*)(tsplit + base + 16 + p * 4) = make_short4(h2[0], h2[1], h2[2], h2[3]);
    *(short4*)(tsplit + base + 32 + p * 4) = make_short4(h3[0], h3[1], h3[2], h3[3]);
  }
}

// ---------------- Kernel 2: 3-buffer rotation + raw barrier + counted vmcnt ---------------
// R10 theory: the 64-VGPR wall is the compiler's LDS-driven occupancy target (36KB -> 4
// blk/CU -> 8 waves/SIMD -> cap 64 -> hot s1/s2 state in AGPRs -> accvgpr round-trips on
// every fmed3/fmax = the unexplained 3x VALU volume). LDS 53,248 B -> 3 blk/CU -> 6
// waves/SIMD target -> cap ~85 -> all-arch allocation. Also: raw s_barrier + s_waitcnt
// vmcnt(2) (counted, T4) instead of __syncthreads: substage sc+1's 2 gloads stay in flight
// across the barrier (only vmcnt ops in this kernel are the staging gloads, so counts are
// exact; nh is LDS). Buffer-reuse safety: a wave issuing into buf[(sc+1)%3] has passed
// barrier(sc-1) => all waves finished compute(sc-2), which read that buffer.
#define SC_H 8

__global__ __launch_bounds__(512, 2) void score_kernel(const short* __restrict__ tsplit,
                                                       const short* __restrict__ bfrag,
                                                       const float* __restrict__ nh_g,
                                                       float4* __restrict__ cand) {
  __shared__ __align__(16) short ldsb[3][8192];  // 3 bufs x 16 KB = 48 KB
  __shared__ float ldsnh[1024];                  // 4 KB -> total 53,248 B
  const int tid = threadIdx.x;
  const int lane = tid & 63;
  const int wv = tid >> 6;  // 0..7
  const int m = lane & 15, q = lane >> 4;
  const int rb = blockIdx.x & 127;
  const int h = blockIdx.x >> 7;  // 0..7
  const int rowbase = rb * 256;

  // A-frags from prepacked tsplit: A12 = [t1|t2]; wave covers rows wv*32 .. wv*32+31
  bf16x8 A12[2];
#pragma unroll
  for (int rt = 0; rt < 2; rt++) {
    int row = rowbase + wv * 32 + rt * 16 + m;
    A12[rt] = *(const bf16x8*)(tsplit + (size_t)row * 48 + q * 8);
  }
  for (int i = tid; i < 1024; i += 512) ldsnh[i] = nh_g[h * 1024 + i];

  // wave wv stages shorts [wv*1024, wv*1024+1024) of each 8-tile (16 KB) substage
  const short* gw = bfrag + (size_t)h * 65536 + wv * 1024 + lane * 8;
  // prologue: stage substage 0 into buf 0
  gload_lds16(gw, &ldsb[0][wv * 1024]);
  gload_lds16(gw + 512, &ldsb[0][wv * 1024 + 512]);

  const unsigned qmask = 0xFFFFFFC0u;
  float s1[2][4], s2[2][4];
#pragma unroll
  for (int rt = 0; rt < 2; rt++)
#pragma unroll
    for (int r = 0; r < 4; r++) { s1[rt][r] = -3.4e38f; s2[rt][r] = -3.4e38f; }

  __syncthreads();  // full drain once: nh + substage-0 visible to all waves

  for (int sc = 0; sc < 8; sc++) {
    if (sc < 7) {  // stage next substage; its 2 loads stay in flight across the barrier
      const short* gs = gw + (sc + 1) * 8192;
      short* ld = &ldsb[(sc + 1) % 3][wv * 1024];
      gload_lds16(gs, ld);
      gload_lds16(gs + 512, ld + 512);
      asm volatile("s_waitcnt vmcnt(2)" ::: "memory");  // my substage-sc loads done
    } else {
      asm volatile("s_waitcnt vmcnt(0)" ::: "memory");
    }
    __builtin_amdgcn_s_barrier();       // all waves' substage-sc writes now in LDS
    asm volatile("" ::: "memory");      // fence: no LDS reads hoisted above the barrier
    const short* bufp = &ldsb[sc % 3][0];
#pragma unroll
    for (int bt = 0; bt < 8; bt++) {
      const short* bp = bufp + bt * 1024;
      bf16x8 b1 = *(const bf16x8*)(bp + lane * 8);
      bf16x8 b2 = *(const bf16x8*)(bp + 512 + lane * 8);
      const int btg = sc * 8 + bt;
      float nh0 = ldsnh[btg * 16 + m];
      f32x4 ci = {nh0, nh0, nh0, nh0};
      const unsigned tagv = (unsigned)(63 - btg);  // prefer low bt on quantized ties
#pragma unroll
      for (int rt = 0; rt < 2; rt++) {
        f32x4 acc = MFMA(A12[rt], b1, ci, 0, 0, 0);
        acc = MFMA(A12[rt], b2, acc, 0, 0, 0);
#pragma unroll
        for (int r = 0; r < 4; r++) {
          float vq = __uint_as_float((__float_as_uint(acc[r]) & qmask) | tagv);
          s2[rt][r] = __builtin_amdgcn_fmed3f(vq, s1[rt][r], s2[rt][r]);
          s1[rt][r] = fmaxf(s1[rt][r], vq);
        }
      }
    }
  }

  // cross-lane top-2 merge over 16 column-lanes; index recovered from tag + ballot
#pragma unroll
  for (int rt = 0; rt < 2; rt++)
#pragma unroll
    for (int r = 0; r < 4; r++) {
      float s1v = s1[rt][r], s2v = s2[rt][r];
      const float ps1 = s1v;  // pre-merge value: identifies the owner lane
#pragma unroll
      for (int msk = 1; msk <= 8; msk <<= 1) {
        float o1 = __shfl_xor(s1v, msk);
        float o2 = __shfl_xor(s2v, msk);
        s2v = __builtin_amdgcn_fmed3f(s1v, o1, fmaxf(s2v, o2));
        s1v = fmaxf(s1v, o1);
      }
      unsigned long long bal = __ballot(ps1 == s1v);
      unsigned grp = (unsigned)((bal >> (q * 16)) & 0xFFFFull);
      int mwin = __builtin_ctz(grp | 0x10000u);  // grp!=0 guaranteed; | is safety
      int btwin = 63 - (int)(__float_as_uint(s1v) & 63u);
      int col = h * 1024 + btwin * 16 + mwin;
      if (m == 0) {
        int row = rowbase + wv * 32 + rt * 16 + q * 4 + r;
        cand[(size_t)h * N_ROWS + row] = make_float4(s1v, s2v, __int_as_float(col), 0.f);
      }
    }
}

// ---------------- Kernel 3a: merge eighths, flag near-ties into compacted list ------------
// eps 1e-3 covers: 2-split error (~2e-4) + mantissa quantization (<=2.4e-4).
#define MARGIN_EPS 1.0e-3f

__global__ __launch_bounds__(256) void merge_flag_kernel(const float4* __restrict__ cand,
                                                         int* __restrict__ out,
                                                         int* __restrict__ list,
                                                         int* __restrict__ ctr) {
  const int r = blockIdx.x * 256 + threadIdx.x;
  float S1 = -3.4e38f, S2 = -3.4e38f;
  int I = 0;
#pragma unroll
  for (int h = 0; h < SC_H; h++) {  // ascending + strict '>' => min index on ties
    float4 v = cand[(size_t)h * N_ROWS + r];
    if (v.x > S1) {
      S2 = fmaxf(S1, v.y); S1 = v.x; I = __float_as_int(v.z);
    } else {
      S2 = fmaxf(S2, v.x);
    }
  }
  out[r] = I;
  if (S1 - S2 < MARGIN_EPS) {
    int slot = atomicAdd(ctr, 1);  // device-scope by default: safe across XCDs
    list[slot] = r;
  }
}

// ---------------- Kernel 3b: exact fp64 rescore, one block per flagged row ----------------
__global__ __launch_bounds__(256) void rescore_kernel(const int* __restrict__ list,
                                                      const int* __restrict__ ctr,
                                                      const float* __restrict__ x,
                                                      const float* __restrict__ w,
                                                      const float* __restrict__ codebook,
                                                      int* __restrict__ out) {
  __shared__ double ps[16][17];
  __shared__ double tsh[16];
  __shared__ double rs[256];
  __shared__ int ri[256];
  const int tid = threadIdx.x;
  const int total = ctr[0];

  for (int it = blockIdx.x; it < total; it += gridDim.x) {
    const int row = list[it];
    {  // exact fp64 t = x_row . W^T
      int o = tid & 15, c = tid >> 4;
      double p = 0.0;
      for (int k = 0; k < 20; k++) {
        int d = c * 20 + k;
        p = fma((double)x[(size_t)row * D_IN + d], (double)w[o * D_IN + d], p);
      }
      ps[c][o] = p;
    }
    __syncthreads();
    if (tid < 16) {
      double t = 0.0;
      for (int c = 0; c < 16; c++) t += ps[c][tid];
      tsh[tid] = t;
    }
    __syncthreads();
    double t[16];
#pragma unroll
    for (int i = 0; i < 16; i++) t[i] = tsh[i];
    double bs = -1.0e300;
    int bi = 0;
    for (int j = tid; j < N_BOOKS; j += 256) {
      const float* cp = codebook + (size_t)j * CB;
      double dot = 0.0, cc = 0.0;
#pragma unroll
      for (int i = 0; i < 16; i++) {
        double cv = (double)cp[i];
        dot = fma(t[i], cv, dot);
        cc = fma(cv, cv, cc);
      }
      double mv = dot - 0.5 * cc;
      if (mv > bs) { bs = mv; bi = j; }  // ascending j: first wins
    }
    rs[tid] = bs; ri[tid] = bi;
    __syncthreads();
    for (int s = 128; s > 0; s >>= 1) {
      if (tid < s) {
        double os = rs[tid + s]; int oi = ri[tid + s];
        if (os > rs[tid] || (os == rs[tid] && oi < ri[tid])) { rs[tid] = os; ri[tid] = oi; }
      }
      __syncthreads();
    }
    if (tid == 0) out[row] = ri[0];
    __syncthreads();  // protect ps/rs reuse on next list item
  }
}

extern "C" void kernel_launch(void* const* d_in, const int* in_sizes, int n_in,
                              void* d_out, int out_size, void* d_ws, size_t ws_size,
                              hipStream_t stream) {
  (void)in_sizes; (void)n_in; (void)out_size; (void)ws_size;
  const float* x = (const float*)d_in[0];
  // d_in[1] = mask_time_indices: all-ones -> flatten; unused
  const float* w = (const float*)d_in[2];
  const float* codebook = (const float*)d_in[3];

  char* ws = (char*)d_ws;
  short* tsplit = (short*)(ws);              // 3 MB   (32768 x 48 shorts)
  short* bfrag = (short*)(ws + (3 << 20));   // 1 MB   (512 bt x 1024 shorts)
  float* nh_g = (float*)(ws + (4 << 20));    // 32 KB
  int* list = (int*)(ws + 4231168);          // 128 KB flagged-row list (4KB pad before)
  int* ctr = (int*)(ws + 4362240);           // 4 B    flagged-row count
  float4* cand = (float4*)(ws + (5 << 20));  // 4 MB   (8 x 32768 x 16 B)
  int* out = (int*)d_out;

  proj_prep_kernel<<<512 + N_BOOKS / 256, 256, 0, stream>>>(x, w, tsplit, codebook, bfrag,
                                                            nh_g, ctr);
  score_kernel<<<128 * SC_H, 512, 0, stream>>>(tsplit, bfrag, nh_g, cand);
  merge_flag_kernel<<<N_ROWS / 256, 256, 0, stream>>>(cand, out, list, ctr);
  rescore_kernel<<<512, 256, 0, stream>>>(list, ctr, x, w, codebook, out);
}